// Round 1
// 924.229 us; speedup vs baseline: 1.0677x; 1.0677x over previous
//
#include <hip/hip_runtime.h>
#include <hip/hip_bf16.h>
#include <stdint.h>

// Problem: act (8192 x 4096) f32, w (4096 x 8192) f32 -> out (8192 x 8192) f32
#define BDIM 8192   // batch rows
#define CIN  4096
#define COUT 8192
#define EPSQ 1e-6f

typedef int v4i __attribute__((ext_vector_type(4)));

#define GLD16_TO_LDS(gp, lp)                                                   \
    __builtin_amdgcn_global_load_lds(                                          \
        (const __attribute__((address_space(1))) void*)(gp),                   \
        (__attribute__((address_space(3))) void*)(lp), 16, 0, 0)

__device__ __forceinline__ int q8i(float x) {
    float r = rintf(x);                 // round-half-to-even == jnp.round
    r = fminf(127.0f, fmaxf(-127.0f, r));
    return (int)r;
}

// ---------------------------------------------------------------------------
// Kernel 1: per-column absmax of act via atomicMax on float bits.
// Candidates are |x| >= 0 so their int bit patterns order like floats, and the
// 0xAAAAAAAA workspace poison is negative -> no init pass needed.
// grid (4, 128), block 256 (2x the parallelism of the 987us version: the
// serial 128-load chain at 1 wave/SIMD was latency-bound).
__global__ void act_absmax_kernel(const float* __restrict__ act,
                                  int* __restrict__ amax_bits) {
    int c4 = (blockIdx.x << 8) + threadIdx.x;   // 0..1023
    int r0 = blockIdx.y << 6;                   // 64 rows/block
    const float4* p = (const float4*)act + (size_t)r0 * (CIN / 4) + c4;
    float mx = 0.f, my = 0.f, mz = 0.f, mw = 0.f;
#pragma unroll 4
    for (int r = 0; r < 64; ++r) {
        float4 v = p[(size_t)r * (CIN / 4)];
        mx = fmaxf(mx, fabsf(v.x));
        my = fmaxf(my, fabsf(v.y));
        mz = fmaxf(mz, fabsf(v.z));
        mw = fmaxf(mw, fabsf(v.w));
    }
    int c = c4 << 2;
    atomicMax(amax_bits + c + 0, __float_as_int(mx));
    atomicMax(amax_bits + c + 1, __float_as_int(my));
    atomicMax(amax_bits + c + 2, __float_as_int(mz));
    atomicMax(amax_bits + c + 3, __float_as_int(mw));
}

// ---------------------------------------------------------------------------
// Kernel 2: quantize act -> int8 (k-contiguous), and write inv_as = 1/act_scale
// (replicating the reference's 1.0/ (127/bound) double division bitwise).
// One thread per float4. grid 32768, block 256.
__global__ void act_quant_kernel(const float4* __restrict__ act4,
                                 const int4* __restrict__ amax_bits4,
                                 float* __restrict__ inv_as,
                                 int* __restrict__ actq_packed) {
    int flat4 = blockIdx.x * 256 + threadIdx.x;       // float4 index
    int c4 = flat4 & ((CIN / 4) - 1);                 // float4 col group
    float4 v = act4[flat4];
    int4 mb = amax_bits4[c4];
    float sx = 127.0f / (__int_as_float(mb.x) + EPSQ);
    float sy = 127.0f / (__int_as_float(mb.y) + EPSQ);
    float sz = 127.0f / (__int_as_float(mb.z) + EPSQ);
    float sw = 127.0f / (__int_as_float(mb.w) + EPSQ);
    int q0 = q8i(v.x * sx), q1 = q8i(v.y * sy), q2 = q8i(v.z * sz), q3 = q8i(v.w * sw);
    int packed = (q0 & 0xff) | ((q1 & 0xff) << 8) | ((q2 & 0xff) << 16) | ((q3 & 0xff) << 24);
    actq_packed[flat4] = packed;
    if (flat4 < CIN / 4) {   // row 0: also emit inv act scale
        int c = c4 << 2;
        inv_as[c + 0] = 1.0f / sx;
        inv_as[c + 1] = 1.0f / sy;
        inv_as[c + 2] = 1.0f / sz;
        inv_as[c + 3] = 1.0f / sw;
    }
}

// ---------------------------------------------------------------------------
// Kernel 3: per-output-column absmax of w_scaled = w * inv_as[k].
// grid (8, 128), block 256 (2x parallelism vs previous).
__global__ void w_absmax_kernel(const float* __restrict__ w,
                                const float* __restrict__ inv_as,
                                int* __restrict__ wmax_bits) {
    int c4 = (blockIdx.x << 8) + threadIdx.x;   // 0..2047
    int k0 = blockIdx.y << 5;                   // 32 rows/block
    const float4* p = (const float4*)w + (size_t)k0 * (COUT / 4) + c4;
    float mx = 0.f, my = 0.f, mz = 0.f, mw = 0.f;
#pragma unroll 4
    for (int r = 0; r < 32; ++r) {
        float ia = inv_as[k0 + r];
        float4 v = p[(size_t)r * (COUT / 4)];
        mx = fmaxf(mx, fabsf(v.x * ia));
        my = fmaxf(my, fabsf(v.y * ia));
        mz = fmaxf(mz, fabsf(v.z * ia));
        mw = fmaxf(mw, fabsf(v.w * ia));
    }
    int c = c4 << 2;
    atomicMax(wmax_bits + c + 0, __float_as_int(mx));
    atomicMax(wmax_bits + c + 1, __float_as_int(my));
    atomicMax(wmax_bits + c + 2, __float_as_int(mz));
    atomicMax(wmax_bits + c + 3, __float_as_int(mw));
}

// ---------------------------------------------------------------------------
// Kernel 4: quantize w and transpose to w_qT (COUT x CIN, k-contiguous int8).
// 64(k) x 64(j) tile through LDS. grid (64, 128), block 256.
__global__ void w_quant_t_kernel(const float* __restrict__ w,
                                 const float* __restrict__ inv_as,
                                 const int* __restrict__ wmax_bits,
                                 signed char* __restrict__ wqT) {
    __shared__ int tile32[16][65];   // [k/4 within tile][j within tile]
    int t = threadIdx.x;
    int k0 = blockIdx.x << 6;
    int j0 = blockIdx.y << 6;
    int tx = t & 63;      // j offset
    int ty = t >> 6;      // 0..3
    int j = j0 + tx;
    float wscale = 127.0f / (__int_as_float(wmax_bits[j]) + EPSQ);
#pragma unroll
    for (int r = 0; r < 4; ++r) {
        int a = r * 4 + ty;            // k-quad index 0..15
        int kb = k0 + (a << 2);
        int packed = 0;
#pragma unroll
        for (int u = 0; u < 4; ++u) {
            int k = kb + u;
            float wsc = w[(size_t)k * COUT + j] * inv_as[k];  // == w_scaled bitwise
            int q = q8i(wsc * wscale);
            packed |= (q & 0xff) << (8 * u);
        }
        tile32[a][tx] = packed;
    }
    __syncthreads();
    // write out: 64 rows of 64 bytes; thread -> (j_loc = t>>2, 16B chunk c = t&3)
    int j_loc = t >> 2;
    int c = t & 3;
    int4 v;
    v.x = tile32[c * 4 + 0][j_loc];
    v.y = tile32[c * 4 + 1][j_loc];
    v.z = tile32[c * 4 + 2][j_loc];
    v.w = tile32[c * 4 + 3][j_loc];
    *(int4*)(wqT + (size_t)(j0 + j_loc) * CIN + k0 + c * 16) = v;
}

// ---------------------------------------------------------------------------
// Kernel 5: int8 NT GEMM (A: BDIM x CIN, B = w_qT: COUT x CIN) + dequant.
//
// 256x256 block tile, 8 waves (512 thr), each wave owns a 128x64 sub-tile
// (8x4 frags of mfma_i32_16x16x64_i8). Deep-pipelined K loop (T1+T3+T4+T5):
//  - LDS = ring of 4 slots per operand; slot = one K-step (K=64 bytes) of the
//    whole 256-row tile, fragment-major (chunk c = g*256+m holds 16B
//    A[m][16g..16g+15]) -> global_load_lds dest is wave-uniform+lane*16 and
//    ds_read_b128 fragment reads are contiguous: bank-conflict-free (measured
//    0 conflicts with this layout at 128-tile).
//  - prefetch depth 3 K-steps; per phase: raw s_barrier -> stage(s+3) ->
//    ds_read frags(s) -> setprio(1) 32xMFMA setprio(0) -> s_waitcnt vmcnt(8).
//    vmcnt(8) retires only step s+1's 4 loads; 8 loads stay in flight across
//    the barrier (counted-vmcnt, never drain-0 in the main loop).
//  - Hazards: slot (s+3)&3 == (s-1)&3 was last read in phase s-1; the
//    top-of-phase-s barrier orders those reads (pinned before their MFMA
//    uses) before the overwrite. vmcnt gate + barrier make step s+1's loads
//    globally visible before any wave reads them in phase s+1.
__global__ __launch_bounds__(512, 2) void gemm_i8_kernel(
    const signed char* __restrict__ Aq,
    const signed char* __restrict__ Bq,
    const int* __restrict__ wmax_bits,
    float* __restrict__ out) {
    __shared__ __align__(16) signed char lds[131072];   // 128 KiB: As 64K | Bs 64K
    signed char* As = lds;
    signed char* Bs = lds + 65536;

    const int tid = threadIdx.x;
    const int wave = tid >> 6;
    const int lane = tid & 63;
    const int g = lane >> 4;           // k-group 0..3 within a K-step
    const int l16 = lane & 15;

    // XCD-aware swizzle: 1024 blocks, 8 XCDs, 128 contiguous tiles per XCD.
    const int bid = blockIdx.x;
    const int swz = (bid & 7) * 128 + (bid >> 3);
    const int bm = (swz >> 5) << 8;    // row-tile
    const int bn = (swz & 31) << 8;    // col-tile

    const int wm128 = (wave >> 2) << 7;   // 0 or 128
    const int wn64 = (wave & 3) << 6;     // 0,64,128,192

    // staging constants: thread tid loads chunk r*512+tid of each half
    // chunk c -> (g_local = c>>8, m = c&255); global k-byte = s*64 + g_local*16
    const int m = tid & 255;
    const int gq = tid >> 8;              // 0 or 1
    const signed char* aP = Aq + ((size_t)(bm + m) << 12) + (gq << 4);
    const signed char* bP = Bq + ((size_t)(bn + m) << 12) + (gq << 4);
    const int ldsOff = tid << 4;

    // fragment read byte offsets within a slot
    const int offA = ((g << 8) + wm128 + l16) << 4;
    const int offB = ((g << 8) + wn64 + l16) << 4;

    v4i acc[8][4] = {};

#define STAGE_STEP(t_)                                                         \
    do {                                                                       \
        signed char* As_ = As + (((t_) & 3) << 14);                            \
        signed char* Bs_ = Bs + (((t_) & 3) << 14);                            \
        const int kb_ = (t_) << 6;                                             \
        GLD16_TO_LDS(aP + kb_,      As_ + ldsOff);                             \
        GLD16_TO_LDS(aP + kb_ + 32, As_ + 8192 + ldsOff);                      \
        GLD16_TO_LDS(bP + kb_,      Bs_ + ldsOff);                             \
        GLD16_TO_LDS(bP + kb_ + 32, Bs_ + 8192 + ldsOff);                      \
    } while (0)

#define COMPUTE_STEP(s_)                                                       \
    do {                                                                       \
        const signed char* Ab_ = As + (((s_) & 3) << 14);                      \
        const signed char* Bb_ = Bs + (((s_) & 3) << 14);                      \
        v4i af_[8], bf_[4];                                                    \
        _Pragma("unroll")                                                      \
        for (int t = 0; t < 8; ++t)                                            \
            af_[t] = *(const v4i*)(Ab_ + offA + (t << 8));                     \
        _Pragma("unroll")                                                      \
        for (int t = 0; t < 4; ++t)                                            \
            bf_[t] = *(const v4i*)(Bb_ + offB + (t << 8));                     \
        __builtin_amdgcn_s_setprio(1);                                         \
        _Pragma("unroll")                                                      \
        for (int tm = 0; tm < 8; ++tm)                                         \
            _Pragma("unroll")                                                  \
            for (int tn = 0; tn < 4; ++tn)                                     \
                acc[tm][tn] = __builtin_amdgcn_mfma_i32_16x16x64_i8(           \
                    af_[tm], bf_[tn], acc[tm][tn], 0, 0, 0);                   \
        __builtin_amdgcn_s_setprio(0);                                         \
    } while (0)

    // prologue: prefetch K-steps 0,1,2 (12 loads); gate step 0 (retire oldest 4)
    STAGE_STEP(0);
    STAGE_STEP(1);
    STAGE_STEP(2);
    asm volatile("s_waitcnt vmcnt(8)" ::: "memory");

#pragma unroll 1
    for (int s = 0; s < 61; ++s) {
        __builtin_amdgcn_s_barrier();          // step s ready for all; slot (s-1)&3 free
        __builtin_amdgcn_sched_barrier(0);
        STAGE_STEP(s + 3);                     // -> slot (s-1)&3
        COMPUTE_STEP(s);
        asm volatile("s_waitcnt vmcnt(8)" ::: "memory");  // retire step s+1's loads
        __builtin_amdgcn_sched_barrier(0);
    }
    // tail: steps 61, 62, 63 (no more staging; drain the counted pipeline)
    __builtin_amdgcn_s_barrier();
    __builtin_amdgcn_sched_barrier(0);
    COMPUTE_STEP(61);
    asm volatile("s_waitcnt vmcnt(4)" ::: "memory");
    __builtin_amdgcn_sched_barrier(0);
    __builtin_amdgcn_s_barrier();
    __builtin_amdgcn_sched_barrier(0);
    COMPUTE_STEP(62);
    asm volatile("s_waitcnt vmcnt(0)" ::: "memory");
    __builtin_amdgcn_sched_barrier(0);
    __builtin_amdgcn_s_barrier();
    __builtin_amdgcn_sched_barrier(0);
    COMPUTE_STEP(63);

#undef STAGE_STEP
#undef COMPUTE_STEP

    // epilogue: dequant by 1/w_scale (recomputed exactly as reference ops)
#pragma unroll
    for (int tn = 0; tn < 4; ++tn) {
        int col = bn + wn64 + (tn << 4) + l16;
        float wscale = 127.0f / (__int_as_float(wmax_bits[col]) + EPSQ);
        float invws = 1.0f / wscale;
#pragma unroll
        for (int tm = 0; tm < 8; ++tm) {
            int row0 = bm + wm128 + (tm << 4) + (g << 2);
#pragma unroll
            for (int r = 0; r < 4; ++r)
                out[((size_t)(row0 + r) << 13) + col] = (float)acc[tm][tn][r] * invws;
        }
    }
}

// ---------------------------------------------------------------------------
extern "C" void kernel_launch(void* const* d_in, const int* in_sizes, int n_in,
                              void* d_out, int out_size, void* d_ws, size_t ws_size,
                              hipStream_t stream) {
    const float* act = (const float*)d_in[0];
    const float* w   = (const float*)d_in[1];
    float* out = (float*)d_out;
    char* ws = (char*)d_ws;

    // workspace layout (~64.06 MB)
    int*   amax_bits = (int*)ws;                                   // 4096 ints
    float* inv_as    = (float*)(ws + 16384);                       // 4096 floats
    int*   wmax_bits = (int*)(ws + 32768);                         // 8192 ints
    signed char* actq = (signed char*)(ws + 65536);                // 8192*4096
    signed char* wqT  = (signed char*)(ws + 65536 + (size_t)BDIM * CIN); // 8192*4096

    act_absmax_kernel<<<dim3(4, 128), 256, 0, stream>>>(act, amax_bits);
    act_quant_kernel<<<(BDIM * CIN / 4) / 256, 256, 0, stream>>>(
        (const float4*)act, (const int4*)amax_bits, inv_as, (int*)actq);
    w_absmax_kernel<<<dim3(8, 128), 256, 0, stream>>>(w, inv_as, wmax_bits);
    w_quant_t_kernel<<<dim3(64, 128), 256, 0, stream>>>(w, inv_as, wmax_bits, wqT);
    gemm_i8_kernel<<<COUT / 256 * (BDIM / 256), 512, 0, stream>>>(
        actq, wqT, wmax_bits, out);
}

// Round 4
// 875.105 us; speedup vs baseline: 1.1276x; 1.0561x over previous
//
#include <hip/hip_runtime.h>
#include <hip/hip_bf16.h>
#include <stdint.h>

// Problem: act (8192 x 4096) f32, w (4096 x 8192) f32 -> out (8192 x 8192) f32
#define BDIM 8192   // batch rows
#define CIN  4096
#define COUT 8192
#define EPSQ 1e-6f

typedef int v4i __attribute__((ext_vector_type(4)));

#define GLD16_TO_LDS(gp, lp)                                                   \
    __builtin_amdgcn_global_load_lds(                                          \
        (const __attribute__((address_space(1))) void*)(gp),                   \
        (__attribute__((address_space(3))) void*)(lp), 16, 0, 0)

__device__ __forceinline__ int q8i(float x) {
    float r = rintf(x);                 // round-half-to-even == jnp.round
    r = fminf(127.0f, fmaxf(-127.0f, r));
    return (int)r;
}

// ---------------------------------------------------------------------------
// Kernel 1: per-column absmax of act via atomicMax on float bits.
// |x| >= 0 so int bit patterns order like floats; 0xAAAAAAAA poison is
// negative -> no init pass. grid (4, 256), block 256 (32 rows/block: TLP for
// the latency-bound load chain).
__global__ void act_absmax_kernel(const float* __restrict__ act,
                                  int* __restrict__ amax_bits) {
    int c4 = (blockIdx.x << 8) + threadIdx.x;   // 0..1023
    int r0 = blockIdx.y << 5;                   // 32 rows/block
    const float4* p = (const float4*)act + (size_t)r0 * (CIN / 4) + c4;
    float mx = 0.f, my = 0.f, mz = 0.f, mw = 0.f;
#pragma unroll 4
    for (int r = 0; r < 32; ++r) {
        float4 v = p[(size_t)r * (CIN / 4)];
        mx = fmaxf(mx, fabsf(v.x));
        my = fmaxf(my, fabsf(v.y));
        mz = fmaxf(mz, fabsf(v.z));
        mw = fmaxf(mw, fabsf(v.w));
    }
    int c = c4 << 2;
    atomicMax(amax_bits + c + 0, __float_as_int(mx));
    atomicMax(amax_bits + c + 1, __float_as_int(my));
    atomicMax(amax_bits + c + 2, __float_as_int(mz));
    atomicMax(amax_bits + c + 3, __float_as_int(mw));
}

// ---------------------------------------------------------------------------
// Kernel 2: quantize act -> int8 (k-contiguous), and write inv_as = 1/act_scale
// (replicating the reference's 1.0/(127/bound) double division bitwise).
__global__ void act_quant_kernel(const float4* __restrict__ act4,
                                 const int4* __restrict__ amax_bits4,
                                 float* __restrict__ inv_as,
                                 int* __restrict__ actq_packed) {
    int flat4 = blockIdx.x * 256 + threadIdx.x;       // float4 index
    int c4 = flat4 & ((CIN / 4) - 1);                 // float4 col group
    float4 v = act4[flat4];
    int4 mb = amax_bits4[c4];
    float sx = 127.0f / (__int_as_float(mb.x) + EPSQ);
    float sy = 127.0f / (__int_as_float(mb.y) + EPSQ);
    float sz = 127.0f / (__int_as_float(mb.z) + EPSQ);
    float sw = 127.0f / (__int_as_float(mb.w) + EPSQ);
    int q0 = q8i(v.x * sx), q1 = q8i(v.y * sy), q2 = q8i(v.z * sz), q3 = q8i(v.w * sw);
    int packed = (q0 & 0xff) | ((q1 & 0xff) << 8) | ((q2 & 0xff) << 16) | ((q3 & 0xff) << 24);
    actq_packed[flat4] = packed;
    if (flat4 < CIN / 4) {   // row 0: also emit inv act scale
        int c = c4 << 2;
        inv_as[c + 0] = 1.0f / sx;
        inv_as[c + 1] = 1.0f / sy;
        inv_as[c + 2] = 1.0f / sz;
        inv_as[c + 3] = 1.0f / sw;
    }
}

// ---------------------------------------------------------------------------
// Kernel 3: per-output-column absmax of w_scaled = w * inv_as[k].
// grid (8, 256), block 256 (16 k-rows/block: TLP).
__global__ void w_absmax_kernel(const float* __restrict__ w,
                                const float* __restrict__ inv_as,
                                int* __restrict__ wmax_bits) {
    int c4 = (blockIdx.x << 8) + threadIdx.x;   // 0..2047
    int k0 = blockIdx.y << 4;                   // 16 rows/block
    const float4* p = (const float4*)w + (size_t)k0 * (COUT / 4) + c4;
    float mx = 0.f, my = 0.f, mz = 0.f, mw = 0.f;
#pragma unroll 4
    for (int r = 0; r < 16; ++r) {
        float ia = inv_as[k0 + r];
        float4 v = p[(size_t)r * (COUT / 4)];
        mx = fmaxf(mx, fabsf(v.x * ia));
        my = fmaxf(my, fabsf(v.y * ia));
        mz = fmaxf(mz, fabsf(v.z * ia));
        mw = fmaxf(mw, fabsf(v.w * ia));
    }
    int c = c4 << 2;
    atomicMax(wmax_bits + c + 0, __float_as_int(mx));
    atomicMax(wmax_bits + c + 1, __float_as_int(my));
    atomicMax(wmax_bits + c + 2, __float_as_int(mz));
    atomicMax(wmax_bits + c + 3, __float_as_int(mw));
}

// ---------------------------------------------------------------------------
// Kernel 4: quantize w and transpose to w_qT (COUT x CIN, k-contiguous).
// 128(k) x 32(j) tile. float4-coalesced loads -> LDS [j][k] (pad 132) ->
// b128 LDS reads -> 128-B coalesced int writes (32 consecutive k-quads/row).
// grid (32, 256), block 256.
__global__ void w_quant_t_kernel(const float* __restrict__ w,
                                 const float* __restrict__ inv_as,
                                 const int* __restrict__ wmax_bits,
                                 signed char* __restrict__ wqT) {
    __shared__ float lf[32 * 132];   // [jj][kk], row stride 132 floats
    int t = threadIdx.x;
    int k0 = blockIdx.x << 7;        // 128 k rows
    int j0 = blockIdx.y << 5;        // 32 j cols
    const float4* w4 = (const float4*)w;
#pragma unroll
    for (int it = 0; it < 4; ++it) {
        int idx = it * 256 + t;       // 0..1023
        int kk = idx >> 3;            // 0..127
        int j4 = idx & 7;             // 0..7
        float4 v = w4[(size_t)(k0 + kk) * (COUT / 4) + (j0 >> 2) + j4];
        lf[(j4 * 4 + 0) * 132 + kk] = v.x;
        lf[(j4 * 4 + 1) * 132 + kk] = v.y;
        lf[(j4 * 4 + 2) * 132 + kk] = v.z;
        lf[(j4 * 4 + 3) * 132 + kk] = v.w;
    }
    __syncthreads();
#pragma unroll
    for (int it = 0; it < 4; ++it) {
        int kq = t & 31;               // k-quad 0..31
        int jl = (t >> 5) + (it << 3); // 0..31
        int j = j0 + jl;
        float wscale = 127.0f / (__int_as_float(wmax_bits[j]) + EPSQ);
        float4 f = *(const float4*)(lf + jl * 132 + (kq << 2));
        int kb = k0 + (kq << 2);
        float w0 = f.x * inv_as[kb + 0];   // == w_scaled bitwise
        float w1 = f.y * inv_as[kb + 1];
        float w2 = f.z * inv_as[kb + 2];
        float w3 = f.w * inv_as[kb + 3];
        int q0 = q8i(w0 * wscale), q1 = q8i(w1 * wscale);
        int q2 = q8i(w2 * wscale), q3 = q8i(w3 * wscale);
        int packed = (q0 & 0xff) | ((q1 & 0xff) << 8) |
                     ((q2 & 0xff) << 16) | ((q3 & 0xff) << 24);
        *(int*)(wqT + (size_t)j * CIN + kb) = packed;
    }
}

// ---------------------------------------------------------------------------
// Kernel 5: int8 NT GEMM (A: BDIM x CIN, B = w_qT: COUT x CIN) + dequant.
//
// 256x256 tile, 8 waves, per-wave 128x64 (8x4 frags of mfma_i32_16x16x64_i8).
// Ring-4 LDS (step = K=64 bytes of the 256-row tile, fragment-major, 32 KiB
// A+B per step, 128 KiB total). Each K-step = TWO sub-phases with issue-ahead
// fragment reads (MFMA consumes regs read in the previous sub-phase; the
// ds_reads' latency spans the barrier under other waves' MFMA):
//   SP0: barrier; stage A(s+3); MFMA tm0-3 (fA0,fB @ s); read fA1(s);
//        vmcnt(6)  [retires step s+1: outstanding s+1(4)+s+2(4)+s+3A(2)=10]
//   SP1: barrier (=> s+1 globally in LDS); stage B(s+3); MFMA tm4-7 (fA1,fB);
//        read fA0(s+1), fB(s+1)
// Slot overwrite safety: stage(s+3) -> slot (s-1)&3; every wave's reads of
// step s-1 are lgkm-retired before its SP1(s-1) MFMA, which precedes the
// SP0(s) barrier that precedes any stage issue.
// Tail: single vmcnt(0)+barrier, then pure compute of steps 61..63 (no LDS
// writes after, so no further barriers/counting — robustness over the <1.5%
// overlap it forgoes).
__global__ __launch_bounds__(512, 2) void gemm_i8_kernel(
    const signed char* __restrict__ Aq,
    const signed char* __restrict__ Bq,
    const int* __restrict__ wmax_bits,
    float* __restrict__ out) {
    __shared__ __align__(16) signed char lds[131072];   // As 64K | Bs 64K
    signed char* As = lds;
    signed char* Bs = lds + 65536;

    const int tid = threadIdx.x;
    const int wave = tid >> 6;
    const int lane = tid & 63;
    const int g = lane >> 4;           // k-group 0..3 within a K-step
    const int l16 = lane & 15;

    // XCD swizzle: 8 XCDs each own a 16(row) x 8(col) tile region; within a
    // region, idx walks row-major so the ~32 concurrent blocks share 4 A-panels
    // + 8 B-panels (k-synchronized slices stay L2-resident).
    const int bid = blockIdx.x;
    const int xcd = bid & 7, idx = bid >> 3;       // 128 tiles per XCD
    const int rg = xcd >> 2, cg = xcd & 3;         // 2x4 XCD region grid
    const int bm = (((rg << 4) + (idx >> 3)) << 8);
    const int bn = (((cg << 3) + (idx & 7)) << 8);

    const int wm128 = (wave >> 2) << 7;   // 0 or 128
    const int wn64 = (wave & 3) << 6;     // 0,64,128,192

    // staging: thread tid loads 2 chunks/operand/step; chunk c = g*256+m holds
    // 16B X[m][16g..16g+15]; c = tid (g = tid>>8) and c = 512+tid (g+2).
    const int m = tid & 255;
    const int gq = tid >> 8;              // 0 or 1
    const signed char* aP = Aq + ((size_t)(bm + m) << 12) + (gq << 4);
    const signed char* bP = Bq + ((size_t)(bn + m) << 12) + (gq << 4);
    const int ldsOff = tid << 4;

    // fragment read byte offsets within a slot
    const int offA = ((g << 8) + wm128 + l16) << 4;
    const int offB = ((g << 8) + wn64 + l16) << 4;

    v4i acc[8][4] = {};
    v4i fA0[4], fA1[4], fB[4];

#define STAGE_A(t_)                                                            \
    do {                                                                       \
        signed char* d_ = As + (((t_) & 3) << 14);                             \
        const int kb_ = (t_) << 6;                                             \
        GLD16_TO_LDS(aP + kb_,      d_ + ldsOff);                              \
        GLD16_TO_LDS(aP + kb_ + 32, d_ + 8192 + ldsOff);                       \
    } while (0)
#define STAGE_B(t_)                                                            \
    do {                                                                       \
        signed char* d_ = Bs + (((t_) & 3) << 14);                             \
        const int kb_ = (t_) << 6;                                             \
        GLD16_TO_LDS(bP + kb_,      d_ + ldsOff);                              \
        GLD16_TO_LDS(bP + kb_ + 32, d_ + 8192 + ldsOff);                       \
    } while (0)
#define READ_FA0(s_)                                                           \
    do {                                                                       \
        const signed char* Ab_ = As + (((s_) & 3) << 14);                      \
        _Pragma("unroll")                                                      \
        for (int t = 0; t < 4; ++t)                                            \
            fA0[t] = *(const v4i*)(Ab_ + offA + (t << 8));                     \
    } while (0)
#define READ_FA1(s_)                                                           \
    do {                                                                       \
        const signed char* Ab_ = As + (((s_) & 3) << 14);                      \
        _Pragma("unroll")                                                      \
        for (int t = 0; t < 4; ++t)                                            \
            fA1[t] = *(const v4i*)(Ab_ + offA + ((t + 4) << 8));               \
    } while (0)
#define READ_FB(s_)                                                            \
    do {                                                                       \
        const signed char* Bb_ = Bs + (((s_) & 3) << 14);                      \
        _Pragma("unroll")                                                      \
        for (int t = 0; t < 4; ++t)                                            \
            fB[t] = *(const v4i*)(Bb_ + offB + (t << 8));                      \
    } while (0)
#define MFMA_LO                                                                \
    do {                                                                       \
        __builtin_amdgcn_s_setprio(1);                                         \
        _Pragma("unroll")                                                      \
        for (int tm = 0; tm < 4; ++tm)                                         \
            _Pragma("unroll")                                                  \
            for (int tn = 0; tn < 4; ++tn)                                     \
                acc[tm][tn] = __builtin_amdgcn_mfma_i32_16x16x64_i8(           \
                    fA0[tm], fB[tn], acc[tm][tn], 0, 0, 0);                    \
        __builtin_amdgcn_s_setprio(0);                                         \
    } while (0)
#define MFMA_HI                                                                \
    do {                                                                       \
        __builtin_amdgcn_s_setprio(1);                                         \
        _Pragma("unroll")                                                      \
        for (int tm = 0; tm < 4; ++tm)                                         \
            _Pragma("unroll")                                                  \
            for (int tn = 0; tn < 4; ++tn)                                     \
                acc[tm + 4][tn] = __builtin_amdgcn_mfma_i32_16x16x64_i8(       \
                    fA1[tm], fB[tn], acc[tm + 4][tn], 0, 0, 0);                \
        __builtin_amdgcn_s_setprio(0);                                         \
    } while (0)

    // prologue: stage steps 0,1,2 in step order (12 loads), gate step 0
    STAGE_A(0); STAGE_B(0);
    STAGE_A(1); STAGE_B(1);
    STAGE_A(2); STAGE_B(2);
    asm volatile("s_waitcnt vmcnt(8)" ::: "memory");
    __builtin_amdgcn_s_barrier();
    READ_FA0(0);
    READ_FB(0);

#pragma unroll 1
    for (int s = 0; s < 61; ++s) {
        // ---- SP0 ----
        __builtin_amdgcn_s_barrier();
        __builtin_amdgcn_sched_barrier(0);
        STAGE_A(s + 3);
        MFMA_LO;
        READ_FA1(s);
        asm volatile("s_waitcnt vmcnt(6)" ::: "memory");   // retire step s+1
        __builtin_amdgcn_sched_barrier(0);
        // ---- SP1 ----
        __builtin_amdgcn_s_barrier();                       // s+1 global in LDS
        __builtin_amdgcn_sched_barrier(0);
        STAGE_B(s + 3);
        MFMA_HI;
        READ_FA0(s + 1);
        READ_FB(s + 1);
        __builtin_amdgcn_sched_barrier(0);
    }

    // ---- tail: steps 61..63, fully drained (simple & robust) ----
    asm volatile("s_waitcnt vmcnt(0)" ::: "memory");  // steps 62,63 written
    __builtin_amdgcn_s_barrier();                     // ... by ALL waves
    __builtin_amdgcn_sched_barrier(0);
    MFMA_LO;                 // step 61 (fA0/fB read in last loop iteration)
    READ_FA1(61);
    MFMA_HI;                 // step 61
    READ_FA0(62); READ_FB(62);
    MFMA_LO;                 // step 62
    READ_FA1(62);
    MFMA_HI;                 // step 62
    READ_FA0(63); READ_FB(63);
    MFMA_LO;                 // step 63
    READ_FA1(63);
    MFMA_HI;                 // step 63

#undef STAGE_A
#undef STAGE_B
#undef READ_FA0
#undef READ_FA1
#undef READ_FB
#undef MFMA_LO
#undef MFMA_HI

    // epilogue: dequant by 1/w_scale (recomputed exactly as reference ops)
#pragma unroll
    for (int tn = 0; tn < 4; ++tn) {
        int col = bn + wn64 + (tn << 4) + l16;
        float wscale = 127.0f / (__int_as_float(wmax_bits[col]) + EPSQ);
        float invws = 1.0f / wscale;
#pragma unroll
        for (int tm = 0; tm < 8; ++tm) {
            int row0 = bm + wm128 + (tm << 4) + (g << 2);
#pragma unroll
            for (int r = 0; r < 4; ++r)
                out[((size_t)(row0 + r) << 13) + col] = (float)acc[tm][tn][r] * invws;
        }
    }
}

// ---------------------------------------------------------------------------
extern "C" void kernel_launch(void* const* d_in, const int* in_sizes, int n_in,
                              void* d_out, int out_size, void* d_ws, size_t ws_size,
                              hipStream_t stream) {
    const float* act = (const float*)d_in[0];
    const float* w   = (const float*)d_in[1];
    float* out = (float*)d_out;
    char* ws = (char*)d_ws;

    // workspace layout (~64.06 MB)
    int*   amax_bits = (int*)ws;                                   // 4096 ints
    float* inv_as    = (float*)(ws + 16384);                       // 4096 floats
    int*   wmax_bits = (int*)(ws + 32768);                         // 8192 ints
    signed char* actq = (signed char*)(ws + 65536);                // 8192*4096
    signed char* wqT  = (signed char*)(ws + 65536 + (size_t)BDIM * CIN); // 8192*4096

    act_absmax_kernel<<<dim3(4, 256), 256, 0, stream>>>(act, amax_bits);
    act_quant_kernel<<<(BDIM * CIN / 4) / 256, 256, 0, stream>>>(
        (const float4*)act, (const int4*)amax_bits, inv_as, (int*)actq);
    w_absmax_kernel<<<dim3(8, 256), 256, 0, stream>>>(w, inv_as, wmax_bits);
    w_quant_t_kernel<<<dim3(32, 256), 256, 0, stream>>>(w, inv_as, wmax_bits, wqT);
    gemm_i8_kernel<<<COUT / 256 * (BDIM / 256), 512, 0, stream>>>(
        actq, wqT, wmax_bits, out);
}